// Round 2
// baseline (5832.515 us; speedup 1.0000x reference)
//
#include <hip/hip_runtime.h>
#include <hip/hip_bf16.h>
#include <math.h>

#define B_    4
#define H_    64
#define W_    128
#define WF_   65
#define D_    768
#define NB_   8
#define BS_   96
#define HID_  3072
#define NTOK_ 32768
#define CHTOK_ 8192
#define LAM_  0.01f

typedef __hip_bfloat16 bf16;

__device__ __forceinline__ float ldf(const float* p) { return *p; }
__device__ __forceinline__ float ldf(const bf16* p)  { return __bfloat162float(*p); }
__device__ __forceinline__ void stf(float* p, float v) { *p = v; }
__device__ __forceinline__ void stf(bf16* p, float v)  { *p = __float2bfloat16(v); }

// ---------------- LayerNorm (one block per token, 768 = 3*256) ----------------
template <typename TIN>
__global__ __launch_bounds__(256) void ln_kernel(
    const TIN* __restrict__ x, const float* __restrict__ g,
    const float* __restrict__ bta, bf16* __restrict__ out) {
  __shared__ float sred[8];
  const size_t base = (size_t)blockIdx.x * D_;
  const int t = threadIdx.x;
  float v0 = ldf(x + base + t);
  float v1 = ldf(x + base + t + 256);
  float v2 = ldf(x + base + t + 512);
  float s = v0 + v1 + v2;
  #pragma unroll
  for (int o = 32; o; o >>= 1) s += __shfl_down(s, o, 64);
  int lane = t & 63, wid = t >> 6;
  if (lane == 0) sred[wid] = s;
  __syncthreads();
  if (t == 0) sred[0] = sred[0] + sred[1] + sred[2] + sred[3];
  __syncthreads();
  float mean = sred[0] * (1.0f / D_);
  float d0 = v0 - mean, d1 = v1 - mean, d2 = v2 - mean;
  float q = d0 * d0 + d1 * d1 + d2 * d2;
  #pragma unroll
  for (int o = 32; o; o >>= 1) q += __shfl_down(q, o, 64);
  if (lane == 0) sred[4 + wid] = q;
  __syncthreads();
  if (t == 0) sred[4] = sred[4] + sred[5] + sred[6] + sred[7];
  __syncthreads();
  float rstd = rsqrtf(sred[4] * (1.0f / D_) + 1e-5f);
  stf(out + base + t,       d0 * rstd * g[t]       + bta[t]);
  stf(out + base + t + 256, d1 * rstd * g[t + 256] + bta[t + 256]);
  stf(out + base + t + 512, d2 * rstd * g[t + 512] + bta[t + 512]);
}

// ---------------- rfft along W as DFT; block = (b,h,f), thread = c ----------------
__global__ __launch_bounds__(256) void rfftw_kernel(
    const bf16* __restrict__ xn, bf16* __restrict__ fr, bf16* __restrict__ fi) {
  __shared__ float shc[W_], shs[W_];
  const int bid = blockIdx.x;           // (b*H + h)*WF + f
  const int f  = bid % WF_;
  const int bh = bid / WF_;
  if (threadIdx.x < W_) {
    int p = (f * threadIdx.x) & (W_ - 1);
    float a = p * 0.04908738521234052f;  // 2*pi/128
    shc[threadIdx.x] = cosf(a);
    shs[threadIdx.x] = sinf(a);
  }
  __syncthreads();
  const bf16* xp = xn + (size_t)bh * W_ * D_ + threadIdx.x;
  float ar0 = 0, ar1 = 0, ar2 = 0, ai0 = 0, ai1 = 0, ai2 = 0;
  for (int w = 0; w < W_; ++w) {
    float er = shc[w], ei = shs[w];
    const bf16* xq = xp + (size_t)w * D_;
    float x0 = ldf(xq), x1 = ldf(xq + 256), x2 = ldf(xq + 512);
    ar0 += er * x0; ar1 += er * x1; ar2 += er * x2;
    ai0 -= ei * x0; ai1 -= ei * x1; ai2 -= ei * x2;
  }
  const float s1 = 0.011048543456039806f;  // 1/sqrt(8192), ortho forward
  size_t ob = (size_t)bid * D_ + threadIdx.x;
  stf(fr + ob, ar0 * s1); stf(fr + ob + 256, ar1 * s1); stf(fr + ob + 512, ar2 * s1);
  stf(fi + ob, ai0 * s1); stf(fi + ob + 256, ai1 * s1); stf(fi + ob + 512, ai2 * s1);
}

// ---------------- FFT along H (complex), esign=-1 fwd / +1 inv ----------------
__global__ __launch_bounds__(256) void ffth_kernel(
    const bf16* __restrict__ inr, const bf16* __restrict__ ini,
    bf16* __restrict__ outr, bf16* __restrict__ outi, float esign) {
  __shared__ float shc[H_], shs[H_];
  const int bid = blockIdx.x;           // (b*H + k)*WF + f
  const int f  = bid % WF_;
  const int bk = bid / WF_;
  const int k  = bk % H_;
  const int b  = bk / H_;
  if (threadIdx.x < H_) {
    int p = (k * threadIdx.x) & (H_ - 1);
    float a = p * 0.09817477042468103f;  // 2*pi/64
    shc[threadIdx.x] = cosf(a);
    shs[threadIdx.x] = esign * sinf(a);
  }
  __syncthreads();
  size_t base = ((size_t)b * H_ * WF_ + f) * D_ + threadIdx.x;
  float ar0 = 0, ar1 = 0, ar2 = 0, ai0 = 0, ai1 = 0, ai2 = 0;
  for (int h = 0; h < H_; ++h) {
    float er = shc[h], ei = shs[h];
    size_t idx = base + (size_t)h * WF_ * D_;
    float xr0 = ldf(inr + idx),       xv0 = ldf(ini + idx);
    float xr1 = ldf(inr + idx + 256), xv1 = ldf(ini + idx + 256);
    float xr2 = ldf(inr + idx + 512), xv2 = ldf(ini + idx + 512);
    ar0 += er * xr0 - ei * xv0;  ai0 += er * xv0 + ei * xr0;
    ar1 += er * xr1 - ei * xv1;  ai1 += er * xv1 + ei * xr1;
    ar2 += er * xr2 - ei * xv2;  ai2 += er * xv2 + ei * xr2;
  }
  size_t ob = (size_t)bid * D_ + threadIdx.x;
  stf(outr + ob, ar0); stf(outr + ob + 256, ar1); stf(outr + ob + 512, ar2);
  stf(outi + ob, ai0); stf(outi + ob + 256, ai1); stf(outi + ob + 512, ai2);
}

// ---------------- per-(b,k,f) block-diagonal complex MLP, in place ----------------
__global__ __launch_bounds__(256) void blockmlp_kernel(
    bf16* __restrict__ gr, bf16* __restrict__ gi,
    const float* __restrict__ w1, const float* __restrict__ b1,
    const float* __restrict__ w2, const float* __restrict__ b2) {
  __shared__ float su[D_], sv[D_], sp[D_], sq[D_];
  const size_t base = (size_t)blockIdx.x * D_;
  #pragma unroll
  for (int s = 0; s < 3; ++s) {
    int c = threadIdx.x + 256 * s;
    float xr = ldf(gr + base + c), xi = ldf(gi + base + c);
    su[c] = xr - xi;
    sv[c] = xr + xi;
  }
  __syncthreads();
  #pragma unroll
  for (int s = 0; s < 3; ++s) {
    int gm = threadIdx.x + 256 * s;
    int nb = gm / BS_;
    int m  = gm - nb * BS_;
    const float* wp = w1 + nb * BS_ * BS_ + m;
    const float* up = su + nb * BS_;
    const float* vp = sv + nb * BS_;
    float a1 = 0, a2 = 0;
    for (int j = 0; j < BS_; ++j) {
      float wv = wp[(size_t)j * BS_];
      a1 += up[j] * wv;
      a2 += vp[j] * wv;
    }
    float bias = b1[gm];
    float o1r = fmaxf(a1 + bias, 0.0f);
    float o1i = fmaxf(a2 + bias, 0.0f);
    sp[gm] = o1r - o1i;
    sq[gm] = o1r + o1i;
  }
  __syncthreads();
  #pragma unroll
  for (int s = 0; s < 3; ++s) {
    int gm = threadIdx.x + 256 * s;
    int nb = gm / BS_;
    int m  = gm - nb * BS_;
    const float* wp = w2 + nb * BS_ * BS_ + m;
    const float* pp = sp + nb * BS_;
    const float* qp = sq + nb * BS_;
    float a1 = 0, a2 = 0;
    for (int j = 0; j < BS_; ++j) {
      float wv = wp[(size_t)j * BS_];
      a1 += pp[j] * wv;
      a2 += qp[j] * wv;
    }
    float bias = b2[gm];
    float o2r = a1 + bias, o2i = a2 + bias;
    o2r = (o2r > LAM_) ? (o2r - LAM_) : ((o2r < -LAM_) ? (o2r + LAM_) : 0.0f);
    o2i = (o2i > LAM_) ? (o2i - LAM_) : ((o2i < -LAM_) ? (o2i + LAM_) : 0.0f);
    stf(gr + base + gm, o2r);
    stf(gi + base + gm, o2i);
  }
}

// ---------------- irfft along W + residual add; block = (b,h,w) = token ----------------
__global__ __launch_bounds__(256) void irfftw_kernel(
    const bf16* __restrict__ fr, const bf16* __restrict__ fi,
    const float* __restrict__ x0, bf16* __restrict__ xsp) {
  __shared__ float shr[WF_], shi[WF_];
  const int bid = blockIdx.x;          // (b*H + h)*W + w == token index
  const int w  = bid & (W_ - 1);
  const int bh = bid >> 7;
  if (threadIdx.x < WF_) {
    int f = threadIdx.x;
    int p = (f * w) & (W_ - 1);
    float a = p * 0.04908738521234052f;
    float al = (f == 0 || f == W_ / 2) ? 1.0f : 2.0f;
    const float s1 = 0.011048543456039806f;  // 1/sqrt(8192), ortho inverse
    shr[f] = s1 * al * cosf(a);
    shi[f] = -s1 * al * sinf(a);
  }
  __syncthreads();
  size_t base = (size_t)bh * WF_ * D_ + threadIdx.x;
  float a0 = 0, a1 = 0, a2 = 0;
  for (int f = 0; f < WF_; ++f) {
    float cr = shr[f], ci = shi[f];
    size_t idx = base + (size_t)f * D_;
    a0 += cr * ldf(fr + idx)       + ci * ldf(fi + idx);
    a1 += cr * ldf(fr + idx + 256) + ci * ldf(fi + idx + 256);
    a2 += cr * ldf(fr + idx + 512) + ci * ldf(fi + idx + 512);
  }
  size_t ob = (size_t)bid * D_ + threadIdx.x;
  stf(xsp + ob,       a0 + x0[ob]);
  stf(xsp + ob + 256, a1 + x0[ob + 256]);
  stf(xsp + ob + 512, a2 + x0[ob + 512]);
}

// ---------------- tiled GEMM: C = act(A @ W + bias) [+ residual] ----------------
// MODE 0: gelu(exact) -> out(bf16) ; MODE 1: + residual -> out(float)
template <int MODE, typename TOUT>
__global__ __launch_bounds__(256) void gemm_kernel(
    const bf16* __restrict__ A, const float* __restrict__ Wm,
    const float* __restrict__ bias, const bf16* __restrict__ resid,
    TOUT* __restrict__ out, int M, int N, int K) {
  __shared__ float As[16][68];  // [k][m], padded
  __shared__ float Bs[16][64];  // [k][n]
  const int tx = threadIdx.x & 15;
  const int ty = threadIdx.x >> 4;
  const int m0 = blockIdx.x * 64;
  const int n0 = blockIdx.y * 64;
  const int am = threadIdx.x >> 2;         // A-tile row this thread loads
  const int ak = (threadIdx.x & 3) * 4;    // A-tile k this thread loads (4 consec)
  const int bk = threadIdx.x >> 4;         // B-tile row
  const int bn = (threadIdx.x & 15) * 4;   // B-tile col (4 consec)
  float acc[4][4] = {};
  for (int k0 = 0; k0 < K; k0 += 16) {
    const bf16* ap = A + (size_t)(m0 + am) * K + k0 + ak;
    #pragma unroll
    for (int u = 0; u < 4; ++u) As[ak + u][am] = ldf(ap + u);
    const float* bp = Wm + (size_t)(k0 + bk) * N + n0 + bn;
    #pragma unroll
    for (int u = 0; u < 4; ++u) Bs[bk][bn + u] = bp[u];
    __syncthreads();
    #pragma unroll
    for (int kk = 0; kk < 16; ++kk) {
      float a[4], bv[4];
      #pragma unroll
      for (int i = 0; i < 4; ++i) a[i] = As[kk][ty * 4 + i];
      #pragma unroll
      for (int j = 0; j < 4; ++j) bv[j] = Bs[kk][tx * 4 + j];
      #pragma unroll
      for (int i = 0; i < 4; ++i)
        #pragma unroll
        for (int j = 0; j < 4; ++j) acc[i][j] += a[i] * bv[j];
    }
    __syncthreads();
  }
  #pragma unroll
  for (int i = 0; i < 4; ++i) {
    int m = m0 + ty * 4 + i;
    #pragma unroll
    for (int j = 0; j < 4; ++j) {
      int n = n0 + tx * 4 + j;
      float v = acc[i][j] + bias[n];
      if (MODE == 0) {
        v = 0.5f * v * (1.0f + erff(v * 0.70710678118654752f));
      } else {
        v += ldf(resid + (size_t)m * N + n);
      }
      stf(out + (size_t)m * N + n, v);
    }
  }
}

extern "C" void kernel_launch(void* const* d_in, const int* in_sizes, int n_in,
                              void* d_out, int out_size, void* d_ws, size_t ws_size,
                              hipStream_t stream) {
  const float* x     = (const float*)d_in[0];
  const float* w1    = (const float*)d_in[1];
  const float* b1    = (const float*)d_in[2];
  const float* w2    = (const float*)d_in[3];
  const float* b2    = (const float*)d_in[4];
  const float* ln1w  = (const float*)d_in[5];
  const float* ln1b  = (const float*)d_in[6];
  const float* ln2w  = (const float*)d_in[7];
  const float* ln2b  = (const float*)d_in[8];
  const float* mlpw1 = (const float*)d_in[9];
  const float* mlpb1 = (const float*)d_in[10];
  const float* mlpw2 = (const float*)d_in[11];
  const float* mlpb2 = (const float*)d_in[12];
  float* out = (float*)d_out;

  const size_t SPA = (size_t)B_ * H_ * W_ * D_;   // 25,165,824 elems
  const size_t FRE = (size_t)B_ * H_ * WF_ * D_;  // 12,779,520 elems
  bf16* ws   = (bf16*)d_ws;
  bf16* bufA = ws;               // xn, later xsp (residual2)
  bf16* Fr   = bufA + SPA;
  bf16* Fi   = Fr + FRE;
  bf16* Gr   = Fi + FRE;
  bf16* Gi   = Gr + FRE;
  bf16* xn2  = Gr;               // overlays Gr+Gi (dead after inverse ffth)
  bf16* hid  = Fr;               // overlays Fr+Fi (dead after irfftw)

  const int nspec = B_ * H_ * WF_;  // 16640

  hipLaunchKernelGGL((ln_kernel<float>), dim3(NTOK_), dim3(256), 0, stream, x, ln1w, ln1b, bufA);
  hipLaunchKernelGGL(rfftw_kernel, dim3(nspec), dim3(256), 0, stream, bufA, Fr, Fi);
  hipLaunchKernelGGL(ffth_kernel, dim3(nspec), dim3(256), 0, stream, Fr, Fi, Gr, Gi, -1.0f);
  hipLaunchKernelGGL(blockmlp_kernel, dim3(nspec), dim3(256), 0, stream, Gr, Gi, w1, b1, w2, b2);
  hipLaunchKernelGGL(ffth_kernel, dim3(nspec), dim3(256), 0, stream, Gr, Gi, Fr, Fi, 1.0f);
  hipLaunchKernelGGL(irfftw_kernel, dim3(NTOK_), dim3(256), 0, stream, Fr, Fi, x, bufA);
  hipLaunchKernelGGL((ln_kernel<bf16>), dim3(NTOK_), dim3(256), 0, stream, bufA, ln2w, ln2b, xn2);
  for (int c = 0; c < B_; ++c) {
    const bf16* a  = xn2 + (size_t)c * CHTOK_ * D_;
    const bf16* rs = bufA + (size_t)c * CHTOK_ * D_;
    float* oc = out + (size_t)c * CHTOK_ * D_;
    hipLaunchKernelGGL((gemm_kernel<0, bf16>), dim3(CHTOK_ / 64, HID_ / 64), dim3(256), 0, stream,
                       a, mlpw1, mlpb1, (const bf16*)nullptr, hid, CHTOK_, HID_, D_);
    hipLaunchKernelGGL((gemm_kernel<1, float>), dim3(CHTOK_ / 64, D_ / 64), dim3(256), 0, stream,
                       hid, mlpw2, mlpb2, rs, oc, CHTOK_, D_, HID_);
  }
}

// Round 3
// 2572.695 us; speedup vs baseline: 2.2671x; 2.2671x over previous
//
#include <hip/hip_runtime.h>
#include <hip/hip_bf16.h>
#include <math.h>

#define B_    4
#define H_    64
#define W_    128
#define WF_   65
#define D_    768
#define NB_   8
#define BS_   96
#define HID_  3072
#define NTOK_ 32768
#define CHTOK_ 8192
#define LAM_  0.01f

typedef __hip_bfloat16 bf16;
typedef __attribute__((ext_vector_type(8))) short bf16x8;
typedef __attribute__((ext_vector_type(4))) float f32x4;
typedef unsigned int u32;

__device__ __forceinline__ float ldf(const float* p) { return *p; }
__device__ __forceinline__ float ldf(const bf16* p)  { return __bfloat162float(*p); }
__device__ __forceinline__ void stf(float* p, float v) { *p = v; }
__device__ __forceinline__ void stf(bf16* p, float v)  { *p = __float2bfloat16(v); }

#define GLOAD_LDS16(g, l) \
  __builtin_amdgcn_global_load_lds((const __attribute__((address_space(1))) u32*)(g), \
                                   (__attribute__((address_space(3))) u32*)(l), 16, 0, 0)

// ---------------- LayerNorm (one block per token, 768 = 3*256) ----------------
template <typename TIN>
__global__ __launch_bounds__(256) void ln_kernel(
    const TIN* __restrict__ x, const float* __restrict__ g,
    const float* __restrict__ bta, bf16* __restrict__ out) {
  __shared__ float sred[8];
  const size_t base = (size_t)blockIdx.x * D_;
  const int t = threadIdx.x;
  float v0 = ldf(x + base + t);
  float v1 = ldf(x + base + t + 256);
  float v2 = ldf(x + base + t + 512);
  float s = v0 + v1 + v2;
  #pragma unroll
  for (int o = 32; o; o >>= 1) s += __shfl_down(s, o, 64);
  int lane = t & 63, wid = t >> 6;
  if (lane == 0) sred[wid] = s;
  __syncthreads();
  if (t == 0) sred[0] = sred[0] + sred[1] + sred[2] + sred[3];
  __syncthreads();
  float mean = sred[0] * (1.0f / D_);
  float d0 = v0 - mean, d1 = v1 - mean, d2 = v2 - mean;
  float q = d0 * d0 + d1 * d1 + d2 * d2;
  #pragma unroll
  for (int o = 32; o; o >>= 1) q += __shfl_down(q, o, 64);
  if (lane == 0) sred[4 + wid] = q;
  __syncthreads();
  if (t == 0) sred[4] = sred[4] + sred[5] + sred[6] + sred[7];
  __syncthreads();
  float rstd = rsqrtf(sred[4] * (1.0f / D_) + 1e-5f);
  stf(out + base + t,       d0 * rstd * g[t]       + bta[t]);
  stf(out + base + t + 256, d1 * rstd * g[t + 256] + bta[t + 256]);
  stf(out + base + t + 512, d2 * rstd * g[t + 512] + bta[t + 512]);
}

// ---------------- rfft along W as DFT; block = (b,h,f), thread = c ----------------
__global__ __launch_bounds__(256) void rfftw_kernel(
    const bf16* __restrict__ xn, bf16* __restrict__ fr, bf16* __restrict__ fi) {
  __shared__ float shc[W_], shs[W_];
  const int bid = blockIdx.x;           // (b*H + h)*WF + f
  const int f  = bid % WF_;
  const int bh = bid / WF_;
  if (threadIdx.x < W_) {
    int p = (f * threadIdx.x) & (W_ - 1);
    float a = p * 0.04908738521234052f;  // 2*pi/128
    shc[threadIdx.x] = cosf(a);
    shs[threadIdx.x] = sinf(a);
  }
  __syncthreads();
  const bf16* xp = xn + (size_t)bh * W_ * D_ + threadIdx.x;
  float ar0 = 0, ar1 = 0, ar2 = 0, ai0 = 0, ai1 = 0, ai2 = 0;
  for (int w = 0; w < W_; ++w) {
    float er = shc[w], ei = shs[w];
    const bf16* xq = xp + (size_t)w * D_;
    float x0 = ldf(xq), x1 = ldf(xq + 256), x2 = ldf(xq + 512);
    ar0 += er * x0; ar1 += er * x1; ar2 += er * x2;
    ai0 -= ei * x0; ai1 -= ei * x1; ai2 -= ei * x2;
  }
  const float s1 = 0.011048543456039806f;  // 1/sqrt(8192), ortho forward
  size_t ob = (size_t)bid * D_ + threadIdx.x;
  stf(fr + ob, ar0 * s1); stf(fr + ob + 256, ar1 * s1); stf(fr + ob + 512, ar2 * s1);
  stf(fi + ob, ai0 * s1); stf(fi + ob + 256, ai1 * s1); stf(fi + ob + 512, ai2 * s1);
}

// ---------------- FFT along H (complex), esign=-1 fwd / +1 inv ----------------
__global__ __launch_bounds__(256) void ffth_kernel(
    const bf16* __restrict__ inr, const bf16* __restrict__ ini,
    bf16* __restrict__ outr, bf16* __restrict__ outi, float esign) {
  __shared__ float shc[H_], shs[H_];
  const int bid = blockIdx.x;           // (b*H + k)*WF + f
  const int f  = bid % WF_;
  const int bk = bid / WF_;
  const int k  = bk % H_;
  const int b  = bk / H_;
  if (threadIdx.x < H_) {
    int p = (k * threadIdx.x) & (H_ - 1);
    float a = p * 0.09817477042468103f;  // 2*pi/64
    shc[threadIdx.x] = cosf(a);
    shs[threadIdx.x] = esign * sinf(a);
  }
  __syncthreads();
  size_t base = ((size_t)b * H_ * WF_ + f) * D_ + threadIdx.x;
  float ar0 = 0, ar1 = 0, ar2 = 0, ai0 = 0, ai1 = 0, ai2 = 0;
  for (int h = 0; h < H_; ++h) {
    float er = shc[h], ei = shs[h];
    size_t idx = base + (size_t)h * WF_ * D_;
    float xr0 = ldf(inr + idx),       xv0 = ldf(ini + idx);
    float xr1 = ldf(inr + idx + 256), xv1 = ldf(ini + idx + 256);
    float xr2 = ldf(inr + idx + 512), xv2 = ldf(ini + idx + 512);
    ar0 += er * xr0 - ei * xv0;  ai0 += er * xv0 + ei * xr0;
    ar1 += er * xr1 - ei * xv1;  ai1 += er * xv1 + ei * xr1;
    ar2 += er * xr2 - ei * xv2;  ai2 += er * xv2 + ei * xr2;
  }
  size_t ob = (size_t)bid * D_ + threadIdx.x;
  stf(outr + ob, ar0); stf(outr + ob + 256, ar1); stf(outr + ob + 512, ar2);
  stf(outi + ob, ai0); stf(outi + ob + 256, ai1); stf(outi + ob + 512, ai2);
}

// ---------------- per-(b,k,f) block-diagonal complex MLP, in place ----------------
__global__ __launch_bounds__(256) void blockmlp_kernel(
    bf16* __restrict__ gr, bf16* __restrict__ gi,
    const float* __restrict__ w1, const float* __restrict__ b1,
    const float* __restrict__ w2, const float* __restrict__ b2) {
  __shared__ float su[D_], sv[D_], sp[D_], sq[D_];
  const size_t base = (size_t)blockIdx.x * D_;
  #pragma unroll
  for (int s = 0; s < 3; ++s) {
    int c = threadIdx.x + 256 * s;
    float xr = ldf(gr + base + c), xi = ldf(gi + base + c);
    su[c] = xr - xi;
    sv[c] = xr + xi;
  }
  __syncthreads();
  #pragma unroll
  for (int s = 0; s < 3; ++s) {
    int gm = threadIdx.x + 256 * s;
    int nb = gm / BS_;
    int m  = gm - nb * BS_;
    const float* wp = w1 + nb * BS_ * BS_ + m;
    const float* up = su + nb * BS_;
    const float* vp = sv + nb * BS_;
    float a1 = 0, a2 = 0;
    for (int j = 0; j < BS_; ++j) {
      float wv = wp[(size_t)j * BS_];
      a1 += up[j] * wv;
      a2 += vp[j] * wv;
    }
    float bias = b1[gm];
    float o1r = fmaxf(a1 + bias, 0.0f);
    float o1i = fmaxf(a2 + bias, 0.0f);
    sp[gm] = o1r - o1i;
    sq[gm] = o1r + o1i;
  }
  __syncthreads();
  #pragma unroll
  for (int s = 0; s < 3; ++s) {
    int gm = threadIdx.x + 256 * s;
    int nb = gm / BS_;
    int m  = gm - nb * BS_;
    const float* wp = w2 + nb * BS_ * BS_ + m;
    const float* pp = sp + nb * BS_;
    const float* qp = sq + nb * BS_;
    float a1 = 0, a2 = 0;
    for (int j = 0; j < BS_; ++j) {
      float wv = wp[(size_t)j * BS_];
      a1 += pp[j] * wv;
      a2 += qp[j] * wv;
    }
    float bias = b2[gm];
    float o2r = a1 + bias, o2i = a2 + bias;
    o2r = (o2r > LAM_) ? (o2r - LAM_) : ((o2r < -LAM_) ? (o2r + LAM_) : 0.0f);
    o2i = (o2i > LAM_) ? (o2i - LAM_) : ((o2i < -LAM_) ? (o2i + LAM_) : 0.0f);
    stf(gr + base + gm, o2r);
    stf(gi + base + gm, o2i);
  }
}

// ---------------- irfft along W + residual add; block = (b,h,w) = token ----------------
__global__ __launch_bounds__(256) void irfftw_kernel(
    const bf16* __restrict__ fr, const bf16* __restrict__ fi,
    const float* __restrict__ x0, bf16* __restrict__ xsp) {
  __shared__ float shr[WF_], shi[WF_];
  const int bid = blockIdx.x;          // (b*H + h)*W + w == token index
  const int w  = bid & (W_ - 1);
  const int bh = bid >> 7;
  if (threadIdx.x < WF_) {
    int f = threadIdx.x;
    int p = (f * w) & (W_ - 1);
    float a = p * 0.04908738521234052f;
    float al = (f == 0 || f == W_ / 2) ? 1.0f : 2.0f;
    const float s1 = 0.011048543456039806f;  // 1/sqrt(8192), ortho inverse
    shr[f] = s1 * al * cosf(a);
    shi[f] = -s1 * al * sinf(a);
  }
  __syncthreads();
  size_t base = (size_t)bh * WF_ * D_ + threadIdx.x;
  float a0 = 0, a1 = 0, a2 = 0;
  for (int f = 0; f < WF_; ++f) {
    float cr = shr[f], ci = shi[f];
    size_t idx = base + (size_t)f * D_;
    a0 += cr * ldf(fr + idx)       + ci * ldf(fi + idx);
    a1 += cr * ldf(fr + idx + 256) + ci * ldf(fi + idx + 256);
    a2 += cr * ldf(fr + idx + 512) + ci * ldf(fi + idx + 512);
  }
  size_t ob = (size_t)bid * D_ + threadIdx.x;
  stf(xsp + ob,       a0 + x0[ob]);
  stf(xsp + ob + 256, a1 + x0[ob + 256]);
  stf(xsp + ob + 512, a2 + x0[ob + 512]);
}

// ---------------- weight transpose+cast: W (K x N fp32, row-major) -> Wt (N x K bf16) ----
__global__ __launch_bounds__(256) void wtrans_kernel(
    const float* __restrict__ Wm, bf16* __restrict__ Wt, int K, int N) {
  __shared__ float tile[32][33];
  const int n0 = blockIdx.x * 32;
  const int k0 = blockIdx.y * 32;
  const int tx = threadIdx.x & 31;
  const int ty = threadIdx.x >> 5;   // 0..7
  #pragma unroll
  for (int r = 0; r < 32; r += 8)
    tile[ty + r][tx] = Wm[(size_t)(k0 + ty + r) * N + n0 + tx];
  __syncthreads();
  #pragma unroll
  for (int r = 0; r < 32; r += 8)
    Wt[(size_t)(n0 + ty + r) * K + k0 + tx] = __float2bfloat16(tile[tx][ty + r]);
}

// ---------------- MFMA GEMM: out = act(A @ Bt^T + bias) [+ resid] ----------------
// A: M x K bf16 row-major. Bt: N x K bf16 row-major. 128x128 tile, BK=32.
// MODE 0: gelu(exact) -> out(bf16) ; MODE 1: + residual(bf16) -> out(float)
template <int MODE, typename TOUT>
__global__ __launch_bounds__(256) void mfma_gemm_kernel(
    const bf16* __restrict__ A, const bf16* __restrict__ Bt,
    const float* __restrict__ bias, const bf16* __restrict__ resid,
    TOUT* __restrict__ out, int M, int N, int K) {
  __shared__ __align__(16) bf16 As[128 * 32];
  __shared__ __align__(16) bf16 Bs[128 * 32];
  const int t = threadIdx.x;
  const int m0 = blockIdx.x * 128;
  const int n0 = blockIdx.y * 128;
  const int wave = t >> 6;
  const int lane = t & 63;
  const int wm = (wave & 1) * 64;    // wave's m-offset in tile
  const int wn = (wave >> 1) * 64;   // wave's n-offset in tile
  const int l16 = lane & 15;
  const int quad = lane >> 4;

  // staging: thread t loads 8 consecutive k-elems (16B) for row t>>2 (and +64)
  const int srow = t >> 2;
  const int skof = (t & 3) * 8;
  const bf16* Ag0 = A + (size_t)(m0 + srow) * K + skof;
  const bf16* Ag1 = A + (size_t)(m0 + 64 + srow) * K + skof;
  const bf16* Bg0 = Bt + (size_t)(n0 + srow) * K + skof;
  const bf16* Bg1 = Bt + (size_t)(n0 + 64 + srow) * K + skof;
  bf16* Al0 = As + t * 8;
  bf16* Al1 = As + 2048 + t * 8;
  bf16* Bl0 = Bs + t * 8;
  bf16* Bl1 = Bs + 2048 + t * 8;

  f32x4 acc[4][4];
  #pragma unroll
  for (int i = 0; i < 4; ++i)
    #pragma unroll
    for (int j = 0; j < 4; ++j) acc[i][j] = (f32x4){0.f, 0.f, 0.f, 0.f};

  for (int k0 = 0; k0 < K; k0 += 32) {
    __syncthreads();   // previous iter's frag reads complete before overwrite
    GLOAD_LDS16(Ag0 + k0, Al0);
    GLOAD_LDS16(Ag1 + k0, Al1);
    GLOAD_LDS16(Bg0 + k0, Bl0);
    GLOAD_LDS16(Bg1 + k0, Bl1);
    __syncthreads();   // drains vmcnt (compiler emits waitcnt before barrier)
    bf16x8 af[4], bfr[4];
    #pragma unroll
    for (int i = 0; i < 4; ++i)
      af[i] = *(const bf16x8*)(As + (wm + i * 16 + l16) * 32 + quad * 8);
    #pragma unroll
    for (int j = 0; j < 4; ++j)
      bfr[j] = *(const bf16x8*)(Bs + (wn + j * 16 + l16) * 32 + quad * 8);
    #pragma unroll
    for (int i = 0; i < 4; ++i)
      #pragma unroll
      for (int j = 0; j < 4; ++j)
        acc[i][j] = __builtin_amdgcn_mfma_f32_16x16x32_bf16(af[i], bfr[j], acc[i][j], 0, 0, 0);
  }

  // epilogue: C/D layout col = lane&15, row = quad*4 + reg
  #pragma unroll
  for (int i = 0; i < 4; ++i) {
    #pragma unroll
    for (int j = 0; j < 4; ++j) {
      const int n = n0 + wn + j * 16 + l16;
      const float bz = bias[n];
      #pragma unroll
      for (int r = 0; r < 4; ++r) {
        const int m = m0 + wm + i * 16 + quad * 4 + r;
        float v = acc[i][j][r] + bz;
        if (MODE == 0) {
          v = 0.5f * v * (1.0f + erff(v * 0.70710678118654752f));
        } else {
          v += ldf(resid + (size_t)m * N + n);
        }
        stf(out + (size_t)m * N + n, v);
      }
    }
  }
}

extern "C" void kernel_launch(void* const* d_in, const int* in_sizes, int n_in,
                              void* d_out, int out_size, void* d_ws, size_t ws_size,
                              hipStream_t stream) {
  const float* x     = (const float*)d_in[0];
  const float* w1    = (const float*)d_in[1];
  const float* b1    = (const float*)d_in[2];
  const float* w2    = (const float*)d_in[3];
  const float* b2    = (const float*)d_in[4];
  const float* ln1w  = (const float*)d_in[5];
  const float* ln1b  = (const float*)d_in[6];
  const float* ln2w  = (const float*)d_in[7];
  const float* ln2b  = (const float*)d_in[8];
  const float* mlpw1 = (const float*)d_in[9];
  const float* mlpb1 = (const float*)d_in[10];
  const float* mlpw2 = (const float*)d_in[11];
  const float* mlpb2 = (const float*)d_in[12];
  float* out = (float*)d_out;

  const size_t SPA = (size_t)B_ * H_ * W_ * D_;   // 25,165,824 elems
  const size_t FRE = (size_t)B_ * H_ * WF_ * D_;  // 12,779,520 elems
  bf16* ws   = (bf16*)d_ws;
  bf16* bufA = ws;               // xn, later xsp (residual2)
  bf16* Fr   = bufA + SPA;
  bf16* Fi   = Fr + FRE;
  bf16* Gr   = Fi + FRE;
  bf16* Gi   = Gr + FRE;
  // GEMM-phase overlays (Fr..Gi dead after irfftw):
  bf16* hid  = Fr;                              // 25,165,824 <= 2*FRE
  bf16* xn2c = Gr;                              // 6,291,456 (per-chunk LN2 out)
  bf16* w1t  = xn2c + (size_t)CHTOK_ * D_;      // 3072 x 768  = 2,359,296
  bf16* w2t  = w1t + (size_t)D_ * HID_;         // 768 x 3072  = 2,359,296  (total < FRE)

  const int nspec = B_ * H_ * WF_;  // 16640

  hipLaunchKernelGGL((ln_kernel<float>), dim3(NTOK_), dim3(256), 0, stream, x, ln1w, ln1b, bufA);
  hipLaunchKernelGGL(rfftw_kernel, dim3(nspec), dim3(256), 0, stream, bufA, Fr, Fi);
  hipLaunchKernelGGL(ffth_kernel, dim3(nspec), dim3(256), 0, stream, Fr, Fi, Gr, Gi, -1.0f);
  hipLaunchKernelGGL(blockmlp_kernel, dim3(nspec), dim3(256), 0, stream, Gr, Gi, w1, b1, w2, b2);
  hipLaunchKernelGGL(ffth_kernel, dim3(nspec), dim3(256), 0, stream, Gr, Gi, Fr, Fi, 1.0f);
  hipLaunchKernelGGL(irfftw_kernel, dim3(NTOK_), dim3(256), 0, stream, Fr, Fi, x, bufA);

  // weight transpose+cast (Gr region is dead now)
  hipLaunchKernelGGL(wtrans_kernel, dim3(HID_ / 32, D_ / 32), dim3(256), 0, stream,
                     mlpw1, w1t, D_, HID_);
  hipLaunchKernelGGL(wtrans_kernel, dim3(D_ / 32, HID_ / 32), dim3(256), 0, stream,
                     mlpw2, w2t, HID_, D_);

  for (int c = 0; c < B_; ++c) {
    const bf16* rs = bufA + (size_t)c * CHTOK_ * D_;
    float* oc = out + (size_t)c * CHTOK_ * D_;
    hipLaunchKernelGGL((ln_kernel<bf16>), dim3(CHTOK_), dim3(256), 0, stream,
                       rs, ln2w, ln2b, xn2c);
    hipLaunchKernelGGL((mfma_gemm_kernel<0, bf16>), dim3(CHTOK_ / 128, HID_ / 128), dim3(256), 0,
                       stream, xn2c, w1t, mlpb1, (const bf16*)nullptr, hid, CHTOK_, HID_, D_);
    hipLaunchKernelGGL((mfma_gemm_kernel<1, float>), dim3(CHTOK_ / 128, D_ / 128), dim3(256), 0,
                       stream, hid, w2t, mlpb2, rs, oc, CHTOK_, D_, HID_);
  }
}

// Round 4
// 1450.778 us; speedup vs baseline: 4.0203x; 1.7733x over previous
//
#include <hip/hip_runtime.h>
#include <hip/hip_bf16.h>
#include <math.h>

#define B_    4
#define H_    64
#define W_    128
#define WF_   65
#define D_    768
#define NB_   8
#define BS_   96
#define HID_  3072
#define NTOK_ 32768
#define CHTOK_ 8192
#define LAM_  0.01f

typedef __hip_bfloat16 bf16;
typedef __attribute__((ext_vector_type(8))) short bf16x8;
typedef __attribute__((ext_vector_type(4))) float f32x4;
typedef unsigned int u32;

__device__ __forceinline__ float ldf(const float* p) { return *p; }
__device__ __forceinline__ float ldf(const bf16* p)  { return __bfloat162float(*p); }
__device__ __forceinline__ void stf(float* p, float v) { *p = v; }
__device__ __forceinline__ void stf(bf16* p, float v)  { *p = __float2bfloat16(v); }

#define GLOAD_LDS16(g, l) \
  __builtin_amdgcn_global_load_lds((const __attribute__((address_space(1))) u32*)(g), \
                                   (__attribute__((address_space(3))) u32*)(l), 16, 0, 0)

// fragment read from LDS row-major [row][Kpad]
#define FRAG(arr, KP, row, kof) (*(const bf16x8*)((arr) + (size_t)(row) * (KP) + (kof)))

// ---------------- LayerNorm (one block per token, 768 = 3*256) ----------------
template <typename TIN>
__global__ __launch_bounds__(256) void ln_kernel(
    const TIN* __restrict__ x, const float* __restrict__ g,
    const float* __restrict__ bta, bf16* __restrict__ out) {
  __shared__ float sred[8];
  const size_t base = (size_t)blockIdx.x * D_;
  const int t = threadIdx.x;
  float v0 = ldf(x + base + t);
  float v1 = ldf(x + base + t + 256);
  float v2 = ldf(x + base + t + 512);
  float s = v0 + v1 + v2;
  #pragma unroll
  for (int o = 32; o; o >>= 1) s += __shfl_down(s, o, 64);
  int lane = t & 63, wid = t >> 6;
  if (lane == 0) sred[wid] = s;
  __syncthreads();
  if (t == 0) sred[0] = sred[0] + sred[1] + sred[2] + sred[3];
  __syncthreads();
  float mean = sred[0] * (1.0f / D_);
  float d0 = v0 - mean, d1 = v1 - mean, d2 = v2 - mean;
  float q = d0 * d0 + d1 * d1 + d2 * d2;
  #pragma unroll
  for (int o = 32; o; o >>= 1) q += __shfl_down(q, o, 64);
  if (lane == 0) sred[4 + wid] = q;
  __syncthreads();
  if (t == 0) sred[4] = sred[4] + sred[5] + sred[6] + sred[7];
  __syncthreads();
  float rstd = rsqrtf(sred[4] * (1.0f / D_) + 1e-5f);
  stf(out + base + t,       d0 * rstd * g[t]       + bta[t]);
  stf(out + base + t + 256, d1 * rstd * g[t + 256] + bta[t + 256]);
  stf(out + base + t + 512, d2 * rstd * g[t + 512] + bta[t + 512]);
}

// ============ S1: rfft along W as MFMA GEMM. block=(bh, ctile64) ============
// Fr/Fi[(bh,f), c] = sum_w C1/C2[f,w] * xn[(bh,w), c]
__global__ __launch_bounds__(256) void s1_rfftw(
    const bf16* __restrict__ xn, bf16* __restrict__ fr, bf16* __restrict__ fi) {
  const int KP = 136;  // 128 + pad (272 B rows, 16B aligned)
  __shared__ __align__(16) bf16 sC1[80 * 136];
  __shared__ __align__(16) bf16 sC2[80 * 136];
  __shared__ __align__(16) bf16 sXt[64 * 136];
  const int t = threadIdx.x;
  const int bh = blockIdx.x;
  const int c0 = blockIdx.y * 64;
  const float s1 = 0.011048543456039806f;  // 1/sqrt(8192)

  // LUT gen: rows f=0..79 (65..79 finite garbage, stores skipped)
  for (int e = t; e < 80 * 128; e += 256) {
    int f = e >> 7, w = e & 127;
    int p = (f * w) & 127;
    float a = p * 0.04908738521234052f;  // 2*pi/128
    sC1[f * KP + w] = __float2bfloat16(s1 * cosf(a));
    sC2[f * KP + w] = __float2bfloat16(-s1 * sinf(a));
  }
  // stage xn tile transposed: sXt[c][w]
  {
    const int cv = (t & 7) * 8;
    #pragma unroll
    for (int rep = 0; rep < 4; ++rep) {
      int w = (t >> 3) + 32 * rep;
      bf16x8 v = *(const bf16x8*)(xn + ((size_t)bh * W_ + w) * D_ + c0 + cv);
      #pragma unroll
      for (int i = 0; i < 8; ++i) sXt[(cv + i) * KP + w] = ((const bf16*)&v)[i];
    }
  }
  __syncthreads();

  const int wave = t >> 6, lane = t & 63, l16 = lane & 15, quad = lane >> 4;
  const int ni = (wave == 0) ? 2 : 1;
  int itile[2] = {wave, 4};
  f32x4 accR[2][4], accI[2][4];
  #pragma unroll
  for (int ii = 0; ii < 2; ++ii)
    #pragma unroll
    for (int j = 0; j < 4; ++j) { accR[ii][j] = (f32x4){0,0,0,0}; accI[ii][j] = (f32x4){0,0,0,0}; }

  for (int s = 0; s < 4; ++s) {
    const int kof = s * 32 + quad * 8;
    bf16x8 bfrag[4];
    #pragma unroll
    for (int j = 0; j < 4; ++j) bfrag[j] = FRAG(sXt, KP, j * 16 + l16, kof);
    for (int ii = 0; ii < ni; ++ii) {
      const int arow = 16 * itile[ii] + l16;
      bf16x8 a1 = FRAG(sC1, KP, arow, kof);
      bf16x8 a2 = FRAG(sC2, KP, arow, kof);
      #pragma unroll
      for (int j = 0; j < 4; ++j) {
        accR[ii][j] = __builtin_amdgcn_mfma_f32_16x16x32_bf16(a1, bfrag[j], accR[ii][j], 0, 0, 0);
        accI[ii][j] = __builtin_amdgcn_mfma_f32_16x16x32_bf16(a2, bfrag[j], accI[ii][j], 0, 0, 0);
      }
    }
  }
  for (int ii = 0; ii < ni; ++ii) {
    #pragma unroll
    for (int r = 0; r < 4; ++r) {
      const int f = 16 * itile[ii] + quad * 4 + r;
      if (f >= WF_) continue;
      const size_t ob = ((size_t)bh * WF_ + f) * D_ + c0;
      #pragma unroll
      for (int j = 0; j < 4; ++j) {
        fr[ob + j * 16 + l16] = __float2bfloat16(accR[ii][j][r]);
        fi[ob + j * 16 + l16] = __float2bfloat16(accI[ii][j][r]);
      }
    }
  }
}

// ============ S2: FFT along H as MFMA GEMM. block=(b*WF+f, ctile64) ============
// G[k,c] = sum_h T[k,h] * F[h,c],  T = exp(esign * i 2pi k h / 64)
__global__ __launch_bounds__(256) void s2_ffth(
    const bf16* __restrict__ inr, const bf16* __restrict__ ini,
    bf16* __restrict__ outr, bf16* __restrict__ outi, float esign) {
  const int KP = 72;  // 64 + pad (144 B rows)
  __shared__ __align__(16) bf16 sTr[64 * 72];
  __shared__ __align__(16) bf16 sTi[64 * 72];
  __shared__ __align__(16) bf16 sTn[64 * 72];
  __shared__ __align__(16) bf16 sFtr[64 * 72];
  __shared__ __align__(16) bf16 sFti[64 * 72];
  const int t = threadIdx.x;
  const int b = blockIdx.x / WF_;
  const int f = blockIdx.x % WF_;
  const int c0 = blockIdx.y * 64;

  for (int e = t; e < 64 * 64; e += 256) {
    int k = e >> 6, h = e & 63;
    int p = (k * h) & 63;
    float a = p * 0.09817477042468103f;  // 2*pi/64
    float c = cosf(a), s = esign * sinf(a);
    sTr[k * KP + h] = __float2bfloat16(c);
    sTi[k * KP + h] = __float2bfloat16(s);
    sTn[k * KP + h] = __float2bfloat16(-s);
  }
  {
    const int cv = (t & 7) * 8;
    #pragma unroll
    for (int rep = 0; rep < 2; ++rep) {
      int h = (t >> 3) + 32 * rep;
      size_t g = ((size_t)(b * H_ + h) * WF_ + f) * D_ + c0 + cv;
      bf16x8 vr = *(const bf16x8*)(inr + g);
      bf16x8 vi = *(const bf16x8*)(ini + g);
      #pragma unroll
      for (int i = 0; i < 8; ++i) {
        sFtr[(cv + i) * KP + h] = ((const bf16*)&vr)[i];
        sFti[(cv + i) * KP + h] = ((const bf16*)&vi)[i];
      }
    }
  }
  __syncthreads();

  const int wave = t >> 6, lane = t & 63, l16 = lane & 15, quad = lane >> 4;
  f32x4 accR[4], accI[4];
  #pragma unroll
  for (int j = 0; j < 4; ++j) { accR[j] = (f32x4){0,0,0,0}; accI[j] = (f32x4){0,0,0,0}; }

  #pragma unroll
  for (int s = 0; s < 2; ++s) {
    const int kof = s * 32 + quad * 8;
    const int arow = 16 * wave + l16;
    bf16x8 ar = FRAG(sTr, KP, arow, kof);
    bf16x8 ai = FRAG(sTi, KP, arow, kof);
    bf16x8 an = FRAG(sTn, KP, arow, kof);
    #pragma unroll
    for (int j = 0; j < 4; ++j) {
      const int brow = j * 16 + l16;
      bf16x8 br = FRAG(sFtr, KP, brow, kof);
      bf16x8 bi = FRAG(sFti, KP, brow, kof);
      accR[j] = __builtin_amdgcn_mfma_f32_16x16x32_bf16(ar, br, accR[j], 0, 0, 0);
      accR[j] = __builtin_amdgcn_mfma_f32_16x16x32_bf16(an, bi, accR[j], 0, 0, 0);
      accI[j] = __builtin_amdgcn_mfma_f32_16x16x32_bf16(ai, br, accI[j], 0, 0, 0);
      accI[j] = __builtin_amdgcn_mfma_f32_16x16x32_bf16(ar, bi, accI[j], 0, 0, 0);
    }
  }
  #pragma unroll
  for (int r = 0; r < 4; ++r) {
    const int k = 16 * wave + quad * 4 + r;
    const size_t ob = ((size_t)(b * H_ + k) * WF_ + f) * D_ + c0;
    #pragma unroll
    for (int j = 0; j < 4; ++j) {
      outr[ob + j * 16 + l16] = __float2bfloat16(accR[j][r]);
      outi[ob + j * 16 + l16] = __float2bfloat16(accI[j][r]);
    }
  }
}

// ============ S3: irfft along W + residual, MFMA. block=(bh, ctile64) ============
// x[w,c] = sum_f Cr[w,f]*Fr[f,c] + Ci[w,f]*Fi[f,c];  K padded 65->96 (zero rows)
__global__ __launch_bounds__(256) void s3_irfftw(
    const bf16* __restrict__ fr, const bf16* __restrict__ fi,
    const float* __restrict__ x0, bf16* __restrict__ xsp) {
  const int KP = 104;  // 96 + pad (208 B rows)
  __shared__ __align__(16) bf16 sCr[128 * 104];
  __shared__ __align__(16) bf16 sCi[128 * 104];
  __shared__ __align__(16) bf16 sGtr[64 * 104];
  __shared__ __align__(16) bf16 sGti[64 * 104];
  const int t = threadIdx.x;
  const int bh = blockIdx.x;
  const int c0 = blockIdx.y * 64;
  const float s1 = 0.011048543456039806f;

  for (int e = t; e < 128 * 96; e += 256) {
    int w = e / 96, f = e - w * 96;
    float cr = 0.f, ci = 0.f;
    if (f < WF_) {
      int p = (f * w) & 127;
      float a = p * 0.04908738521234052f;
      float al = (f == 0 || f == 64) ? 1.0f : 2.0f;
      cr = s1 * al * cosf(a);
      ci = -s1 * al * sinf(a);
    }
    sCr[w * KP + f] = __float2bfloat16(cr);
    sCi[w * KP + f] = __float2bfloat16(ci);
  }
  {
    const int cv = (t & 7) * 8;
    #pragma unroll
    for (int rep = 0; rep < 2; ++rep) {
      int f = (t >> 3) + 32 * rep;
      size_t g = ((size_t)bh * WF_ + f) * D_ + c0 + cv;
      bf16x8 vr = *(const bf16x8*)(fr + g);
      bf16x8 vi = *(const bf16x8*)(fi + g);
      #pragma unroll
      for (int i = 0; i < 8; ++i) {
        sGtr[(cv + i) * KP + f] = ((const bf16*)&vr)[i];
        sGti[(cv + i) * KP + f] = ((const bf16*)&vi)[i];
      }
    }
    if (t < 8) {  // f = 64 row
      size_t g = ((size_t)bh * WF_ + 64) * D_ + c0 + cv;
      bf16x8 vr = *(const bf16x8*)(fr + g);
      bf16x8 vi = *(const bf16x8*)(fi + g);
      #pragma unroll
      for (int i = 0; i < 8; ++i) {
        sGtr[(cv + i) * KP + 64] = ((const bf16*)&vr)[i];
        sGti[(cv + i) * KP + 64] = ((const bf16*)&vi)[i];
      }
    }
    // zero pad rows f=65..95 (avoid NaN from poisoned LDS)
    const bf16 z = __float2bfloat16(0.f);
    for (int e = t; e < 64 * 31; e += 256) {
      int c = e / 31, f = 65 + (e - (e / 31) * 31);
      sGtr[c * KP + f] = z;
      sGti[c * KP + f] = z;
    }
  }
  __syncthreads();

  const int wave = t >> 6, lane = t & 63, l16 = lane & 15, quad = lane >> 4;
  f32x4 acc[2][4];
  #pragma unroll
  for (int ii = 0; ii < 2; ++ii)
    #pragma unroll
    for (int j = 0; j < 4; ++j) acc[ii][j] = (f32x4){0,0,0,0};

  #pragma unroll
  for (int s = 0; s < 3; ++s) {
    const int kof = s * 32 + quad * 8;
    bf16x8 br[4], bi[4];
    #pragma unroll
    for (int j = 0; j < 4; ++j) {
      br[j] = FRAG(sGtr, KP, j * 16 + l16, kof);
      bi[j] = FRAG(sGti, KP, j * 16 + l16, kof);
    }
    #pragma unroll
    for (int ii = 0; ii < 2; ++ii) {
      const int arow = 16 * (wave + 4 * ii) + l16;
      bf16x8 a1 = FRAG(sCr, KP, arow, kof);
      bf16x8 a2 = FRAG(sCi, KP, arow, kof);
      #pragma unroll
      for (int j = 0; j < 4; ++j) {
        acc[ii][j] = __builtin_amdgcn_mfma_f32_16x16x32_bf16(a1, br[j], acc[ii][j], 0, 0, 0);
        acc[ii][j] = __builtin_amdgcn_mfma_f32_16x16x32_bf16(a2, bi[j], acc[ii][j], 0, 0, 0);
      }
    }
  }
  #pragma unroll
  for (int ii = 0; ii < 2; ++ii) {
    #pragma unroll
    for (int r = 0; r < 4; ++r) {
      const int w = 16 * (wave + 4 * ii) + quad * 4 + r;
      const size_t ob = ((size_t)bh * W_ + w) * D_ + c0;
      #pragma unroll
      for (int j = 0; j < 4; ++j) {
        const size_t o = ob + j * 16 + l16;
        xsp[o] = __float2bfloat16(acc[ii][j][r] + x0[o]);
      }
    }
  }
}

// ---------------- per-(b,k,f) block-diagonal complex MLP, in place ----------------
__global__ __launch_bounds__(256) void blockmlp_kernel(
    bf16* __restrict__ gr, bf16* __restrict__ gi,
    const float* __restrict__ w1, const float* __restrict__ b1,
    const float* __restrict__ w2, const float* __restrict__ b2) {
  __shared__ float su[D_], sv[D_], sp[D_], sq[D_];
  const size_t base = (size_t)blockIdx.x * D_;
  #pragma unroll
  for (int s = 0; s < 3; ++s) {
    int c = threadIdx.x + 256 * s;
    float xr = ldf(gr + base + c), xi = ldf(gi + base + c);
    su[c] = xr - xi;
    sv[c] = xr + xi;
  }
  __syncthreads();
  #pragma unroll
  for (int s = 0; s < 3; ++s) {
    int gm = threadIdx.x + 256 * s;
    int nb = gm / BS_;
    int m  = gm - nb * BS_;
    const float* wp = w1 + nb * BS_ * BS_ + m;
    const float* up = su + nb * BS_;
    const float* vp = sv + nb * BS_;
    float a1 = 0, a2 = 0;
    for (int j = 0; j < BS_; ++j) {
      float wv = wp[(size_t)j * BS_];
      a1 += up[j] * wv;
      a2 += vp[j] * wv;
    }
    float bias = b1[gm];
    float o1r = fmaxf(a1 + bias, 0.0f);
    float o1i = fmaxf(a2 + bias, 0.0f);
    sp[gm] = o1r - o1i;
    sq[gm] = o1r + o1i;
  }
  __syncthreads();
  #pragma unroll
  for (int s = 0; s < 3; ++s) {
    int gm = threadIdx.x + 256 * s;
    int nb = gm / BS_;
    int m  = gm - nb * BS_;
    const float* wp = w2 + nb * BS_ * BS_ + m;
    const float* pp = sp + nb * BS_;
    const float* qp = sq + nb * BS_;
    float a1 = 0, a2 = 0;
    for (int j = 0; j < BS_; ++j) {
      float wv = wp[(size_t)j * BS_];
      a1 += pp[j] * wv;
      a2 += qp[j] * wv;
    }
    float bias = b2[gm];
    float o2r = a1 + bias, o2i = a2 + bias;
    o2r = (o2r > LAM_) ? (o2r - LAM_) : ((o2r < -LAM_) ? (o2r + LAM_) : 0.0f);
    o2i = (o2i > LAM_) ? (o2i - LAM_) : ((o2i < -LAM_) ? (o2i + LAM_) : 0.0f);
    stf(gr + base + gm, o2r);
    stf(gi + base + gm, o2i);
  }
}

// ---------------- weight transpose+cast: W (K x N fp32) -> Wt (N x K bf16) ----
__global__ __launch_bounds__(256) void wtrans_kernel(
    const float* __restrict__ Wm, bf16* __restrict__ Wt, int K, int N) {
  __shared__ float tile[32][33];
  const int n0 = blockIdx.x * 32;
  const int k0 = blockIdx.y * 32;
  const int tx = threadIdx.x & 31;
  const int ty = threadIdx.x >> 5;   // 0..7
  #pragma unroll
  for (int r = 0; r < 32; r += 8)
    tile[ty + r][tx] = Wm[(size_t)(k0 + ty + r) * N + n0 + tx];
  __syncthreads();
  #pragma unroll
  for (int r = 0; r < 32; r += 8)
    Wt[(size_t)(n0 + ty + r) * K + k0 + tx] = __float2bfloat16(tile[tx][ty + r]);
}

// ---------------- MFMA GEMM: out = act(A @ Bt^T + bias) [+ resid] ----------------
template <int MODE, typename TOUT>
__global__ __launch_bounds__(256) void mfma_gemm_kernel(
    const bf16* __restrict__ A, const bf16* __restrict__ Bt,
    const float* __restrict__ bias, const bf16* __restrict__ resid,
    TOUT* __restrict__ out, int M, int N, int K) {
  __shared__ __align__(16) bf16 As[128 * 32];
  __shared__ __align__(16) bf16 Bs[128 * 32];
  const int t = threadIdx.x;
  const int m0 = blockIdx.x * 128;
  const int n0 = blockIdx.y * 128;
  const int wave = t >> 6;
  const int lane = t & 63;
  const int wm = (wave & 1) * 64;
  const int wn = (wave >> 1) * 64;
  const int l16 = lane & 15;
  const int quad = lane >> 4;

  const int srow = t >> 2;
  const int skof = (t & 3) * 8;
  const bf16* Ag0 = A + (size_t)(m0 + srow) * K + skof;
  const bf16* Ag1 = A + (size_t)(m0 + 64 + srow) * K + skof;
  const bf16* Bg0 = Bt + (size_t)(n0 + srow) * K + skof;
  const bf16* Bg1 = Bt + (size_t)(n0 + 64 + srow) * K + skof;
  bf16* Al0 = As + t * 8;
  bf16* Al1 = As + 2048 + t * 8;
  bf16* Bl0 = Bs + t * 8;
  bf16* Bl1 = Bs + 2048 + t * 8;

  f32x4 acc[4][4];
  #pragma unroll
  for (int i = 0; i < 4; ++i)
    #pragma unroll
    for (int j = 0; j < 4; ++j) acc[i][j] = (f32x4){0.f, 0.f, 0.f, 0.f};

  for (int k0 = 0; k0 < K; k0 += 32) {
    __syncthreads();
    GLOAD_LDS16(Ag0 + k0, Al0);
    GLOAD_LDS16(Ag1 + k0, Al1);
    GLOAD_LDS16(Bg0 + k0, Bl0);
    GLOAD_LDS16(Bg1 + k0, Bl1);
    __syncthreads();
    bf16x8 af[4], bfr[4];
    #pragma unroll
    for (int i = 0; i < 4; ++i)
      af[i] = *(const bf16x8*)(As + (wm + i * 16 + l16) * 32 + quad * 8);
    #pragma unroll
    for (int j = 0; j < 4; ++j)
      bfr[j] = *(const bf16x8*)(Bs + (wn + j * 16 + l16) * 32 + quad * 8);
    #pragma unroll
    for (int i = 0; i < 4; ++i)
      #pragma unroll
      for (int j = 0; j < 4; ++j)
        acc[i][j] = __builtin_amdgcn_mfma_f32_16x16x32_bf16(af[i], bfr[j], acc[i][j], 0, 0, 0);
  }

  #pragma unroll
  for (int i = 0; i < 4; ++i) {
    #pragma unroll
    for (int j = 0; j < 4; ++j) {
      const int n = n0 + wn + j * 16 + l16;
      const float bz = bias[n];
      #pragma unroll
      for (int r = 0; r < 4; ++r) {
        const int m = m0 + wm + i * 16 + quad * 4 + r;
        float v = acc[i][j][r] + bz;
        if (MODE == 0) {
          v = 0.5f * v * (1.0f + erff(v * 0.70710678118654752f));
        } else {
          v += ldf(resid + (size_t)m * N + n);
        }
        stf(out + (size_t)m * N + n, v);
      }
    }
  }
}

extern "C" void kernel_launch(void* const* d_in, const int* in_sizes, int n_in,
                              void* d_out, int out_size, void* d_ws, size_t ws_size,
                              hipStream_t stream) {
  const float* x     = (const float*)d_in[0];
  const float* w1    = (const float*)d_in[1];
  const float* b1    = (const float*)d_in[2];
  const float* w2    = (const float*)d_in[3];
  const float* b2    = (const float*)d_in[4];
  const float* ln1w  = (const float*)d_in[5];
  const float* ln1b  = (const float*)d_in[6];
  const float* ln2w  = (const float*)d_in[7];
  const float* ln2b  = (const float*)d_in[8];
  const float* mlpw1 = (const float*)d_in[9];
  const float* mlpb1 = (const float*)d_in[10];
  const float* mlpw2 = (const float*)d_in[11];
  const float* mlpb2 = (const float*)d_in[12];
  float* out = (float*)d_out;

  const size_t SPA = (size_t)B_ * H_ * W_ * D_;   // 25,165,824 elems
  const size_t FRE = (size_t)B_ * H_ * WF_ * D_;  // 12,779,520 elems
  bf16* ws   = (bf16*)d_ws;
  bf16* bufA = ws;               // xn, later xsp (residual2)
  bf16* Fr   = bufA + SPA;
  bf16* Fi   = Fr + FRE;
  bf16* Gr   = Fi + FRE;
  bf16* Gi   = Gr + FRE;
  bf16* hid  = Fr;                              // GEMM-phase overlays
  bf16* xn2c = Gr;
  bf16* w1t  = xn2c + (size_t)CHTOK_ * D_;
  bf16* w2t  = w1t + (size_t)D_ * HID_;

  const int nspec = B_ * H_ * WF_;  // 16640

  hipLaunchKernelGGL((ln_kernel<float>), dim3(NTOK_), dim3(256), 0, stream, x, ln1w, ln1b, bufA);
  hipLaunchKernelGGL(s1_rfftw, dim3(B_ * H_, D_ / 64), dim3(256), 0, stream, bufA, Fr, Fi);
  hipLaunchKernelGGL(s2_ffth, dim3(B_ * WF_, D_ / 64), dim3(256), 0, stream,
                     Fr, Fi, Gr, Gi, -1.0f);
  hipLaunchKernelGGL(blockmlp_kernel, dim3(nspec), dim3(256), 0, stream, Gr, Gi, w1, b1, w2, b2);
  hipLaunchKernelGGL(s2_ffth, dim3(B_ * WF_, D_ / 64), dim3(256), 0, stream,
                     Gr, Gi, Fr, Fi, 1.0f);
  hipLaunchKernelGGL(s3_irfftw, dim3(B_ * H_, D_ / 64), dim3(256), 0, stream, Fr, Fi, x, bufA);

  hipLaunchKernelGGL(wtrans_kernel, dim3(HID_ / 32, D_ / 32), dim3(256), 0, stream,
                     mlpw1, w1t, D_, HID_);
  hipLaunchKernelGGL(wtrans_kernel, dim3(D_ / 32, HID_ / 32), dim3(256), 0, stream,
                     mlpw2, w2t, HID_, D_);

  for (int c = 0; c < B_; ++c) {
    const bf16* rs = bufA + (size_t)c * CHTOK_ * D_;
    float* oc = out + (size_t)c * CHTOK_ * D_;
    hipLaunchKernelGGL((ln_kernel<bf16>), dim3(CHTOK_), dim3(256), 0, stream,
                       rs, ln2w, ln2b, xn2c);
    hipLaunchKernelGGL((mfma_gemm_kernel<0, bf16>), dim3(CHTOK_ / 128, HID_ / 128), dim3(256), 0,
                       stream, xn2c, w1t, mlpb1, (const bf16*)nullptr, hid, CHTOK_, HID_, D_);
    hipLaunchKernelGGL((mfma_gemm_kernel<1, float>), dim3(CHTOK_ / 128, D_ / 128), dim3(256), 0,
                       stream, hid, w2t, mlpb2, rs, oc, CHTOK_, D_, HID_);
  }
}